// Round 1
// baseline (3003.198 us; speedup 1.0000x reference)
//
#include <hip/hip_runtime.h>
#include <math.h>

#define NFULL 1024
#define CDIM  512
#define HD    64
#define NH    8
#define TI    16
#define TJ    128

// ---------------- bucket ids ----------------
__device__ __forceinline__ int pwidx(int d) {
  int ad = d < 0 ? -d : d;
  if (ad <= 1) return d;                       // |d| <= 1.9, d integer
  float v = 1.9f + logf((float)ad * (1.0f / 1.9f)) * (1.9f / 2.0794415416798357f); // ln(8)
  v = fminf(v, 3.8f);
  int m = (int)rintf(v);                       // round-half-even, matches jnp.round
  if (m > 4) m = 4;
  return d > 0 ? m : -m;
}

__global__ __launch_bounds__(256) void bucket_kernel(int* __restrict__ bucket) {
  int idx = blockIdx.x * 256 + threadIdx.x;    // over N*N
  int i = idx >> 10, j = idx & 1023;
  int iy = i >> 5, ix = i & 31, jy = j >> 5, jx = j & 31;
  bucket[idx] = (pwidx(iy - jy) + 4) * 9 + (pwidx(ix - jx) + 4);
}

// ---------------- layernorm (one block per row of 512) ----------------
__global__ __launch_bounds__(256) void ln_kernel(const float* __restrict__ x,
                                                 const float* __restrict__ g,
                                                 const float* __restrict__ be,
                                                 float* __restrict__ y) {
  __shared__ float red[8];
  int row = blockIdx.x, tid = threadIdx.x;
  const float* xr = x + (size_t)row * CDIM;
  float v0 = xr[tid], v1 = xr[tid + 256];
  float s = v0 + v1;
#pragma unroll
  for (int off = 32; off; off >>= 1) s += __shfl_xor(s, off);
  int wid = tid >> 6, lane = tid & 63;
  if (!lane) red[wid] = s;
  __syncthreads();
  float mu = (red[0] + red[1] + red[2] + red[3]) * (1.0f / 512.0f);
  float d0 = v0 - mu, d1 = v1 - mu;
  float q = d0 * d0 + d1 * d1;
#pragma unroll
  for (int off = 32; off; off >>= 1) q += __shfl_xor(q, off);
  if (!lane) red[4 + wid] = q;
  __syncthreads();
  float var = (red[4] + red[5] + red[6] + red[7]) * (1.0f / 512.0f);
  float rstd = rsqrtf(var + 1e-5f);
  float* yr = y + (size_t)row * CDIM;
  yr[tid]       = d0 * rstd * g[tid]       + be[tid];
  yr[tid + 256] = d1 * rstd * g[tid + 256] + be[tid + 256];
}

// ---------------- generic fp32 GEMM: C = act(A@B + bias) (+res) ----------------
__device__ __forceinline__ float gelu_f(float x) {
  return 0.5f * x * (1.0f + erff(x * 0.7071067811865475f));
}

template <int RG, int CG, int ACT, int RES>
__global__ __launch_bounds__(256) void gemm_f32(const float* __restrict__ A,
                                                const float* __restrict__ Bm,
                                                const float* __restrict__ bias,
                                                const float* __restrict__ res,
                                                float* __restrict__ C,
                                                int M, int N, int K) {
  constexpr int BM = 64 * RG, BN = 64 * CG, BK = 32;
  __shared__ __attribute__((aligned(16))) float As[BK][BM + 4];  // transposed: As[k][m]
  __shared__ __attribute__((aligned(16))) float Bs[BK][BN + 4];
  const int tid = threadIdx.x;
  const int bm = blockIdx.y * BM, bn = blockIdx.x * BN;
  const int ty = tid >> 4, tx = tid & 15;
  float acc[4 * RG][4 * CG] = {};

  for (int k0 = 0; k0 < K; k0 += BK) {
    __syncthreads();
#pragma unroll
    for (int it = 0; it < RG * 2; ++it) {
      int e = tid + it * 256;
      int ar = e >> 3, ac = (e & 7) * 4;
      float4 av = *(const float4*)(A + (size_t)(bm + ar) * K + k0 + ac);
      As[ac + 0][ar] = av.x; As[ac + 1][ar] = av.y;
      As[ac + 2][ar] = av.z; As[ac + 3][ar] = av.w;
    }
#pragma unroll
    for (int it = 0; it < CG * 2; ++it) {
      int e = tid + it * 256;
      int br, bc;
      if (CG == 2) { br = e >> 5; bc = (e & 31) * 4; }
      else         { br = e >> 4; bc = (e & 15) * 4; }
      *(float4*)&Bs[br][bc] = *(const float4*)(Bm + (size_t)(k0 + br) * N + bn + bc);
    }
    __syncthreads();
#pragma unroll
    for (int kk = 0; kk < BK; ++kk) {
      float a[4 * RG], b[4 * CG];
#pragma unroll
      for (int rg = 0; rg < RG; ++rg)
        *(float4*)&a[rg * 4] = *(const float4*)&As[kk][(ty + 16 * rg) * 4];
#pragma unroll
      for (int cg = 0; cg < CG; ++cg)
        *(float4*)&b[cg * 4] = *(const float4*)&Bs[kk][(tx + 16 * cg) * 4];
#pragma unroll
      for (int i = 0; i < 4 * RG; ++i)
#pragma unroll
        for (int j = 0; j < 4 * CG; ++j)
          acc[i][j] = fmaf(a[i], b[j], acc[i][j]);
    }
  }
  // epilogue
  float bv[4 * CG];
#pragma unroll
  for (int cg = 0; cg < CG; ++cg)
    *(float4*)&bv[cg * 4] = *(const float4*)(bias + bn + (tx + 16 * cg) * 4);
#pragma unroll
  for (int rg = 0; rg < RG; ++rg) {
#pragma unroll
    for (int r = 0; r < 4; ++r) {
      int row = bm + (ty + 16 * rg) * 4 + r;
#pragma unroll
      for (int cg = 0; cg < CG; ++cg) {
        int col = bn + (tx + 16 * cg) * 4;
        float o[4];
#pragma unroll
        for (int c = 0; c < 4; ++c) {
          float v = acc[rg * 4 + r][cg * 4 + c] + bv[cg * 4 + c];
          if (ACT == 1) v = gelu_f(v);
          o[c] = v;
        }
        if (RES) {
          float rr[4];
          *(float4*)rr = *(const float4*)(res + (size_t)row * N + col);
#pragma unroll
          for (int c = 0; c < 4; ++c) o[c] += rr[c];
        }
        *(float4*)(C + (size_t)row * N + col) = *(float4*)o;
      }
    }
  }
}

// ---------------- table products: out[b,h,i,c] = scl * dot(X[b,i,h*64:+64], T[c,:]) ----------------
__global__ __launch_bounds__(256) void tableprod_kernel(const float* __restrict__ X, int ldx,
                                                        const float* __restrict__ T,
                                                        float* __restrict__ out, float scl) {
  __shared__ __attribute__((aligned(16))) float Ts[81 * 65];
  __shared__ __attribute__((aligned(16))) float xr[512];
  int r = blockIdx.x;  // b*N + i
  int tid = threadIdx.x;
  for (int f = tid; f < 81 * 64; f += 256) Ts[(f >> 6) * 65 + (f & 63)] = T[f];
  xr[tid]       = X[(size_t)r * ldx + tid];
  xr[tid + 256] = X[(size_t)r * ldx + tid + 256];
  __syncthreads();
  int b = r >> 10, i = r & 1023;
  for (int f = tid; f < NH * 81; f += 256) {
    int hh = f / 81, c = f - hh * 81;
    const float* xp = &xr[hh * 64];
    const float* tp = &Ts[c * 65];
    float dot = 0.f;
#pragma unroll
    for (int d = 0; d < 64; ++d) dot = fmaf(xp[d], tp[d], dot);
    out[((size_t)(b * NH + hh) * NFULL + i) * 81 + c] = dot * scl;
  }
}

// ---------------- fused attention ----------------
// per block: (b, h, 16 q-rows). scores in LDS, online over j-tiles of 128.
__global__ __launch_bounds__(256) void attn_kernel(const float* __restrict__ q,
                                                   const float* __restrict__ k,
                                                   const float* __restrict__ v,
                                                   int ld,
                                                   const float* __restrict__ lk,
                                                   const float* __restrict__ lq,
                                                   const int* __restrict__ bucket,
                                                   const float* __restrict__ tv,
                                                   float* __restrict__ o) {
  __shared__ __attribute__((aligned(16))) float sc[TI][NFULL + 4];
  __shared__ __attribute__((aligned(16))) float kvf[TJ * HD];
  __shared__ __attribute__((aligned(16))) float qbuf[TI][HD];
  __shared__ float lkb[TI][81];
  __shared__ float wb[TI][81];
  __shared__ float rowsum[TI];

  const int tid = threadIdx.x;
  const int i0 = blockIdx.x * TI;
  const int h = blockIdx.y;
  const int b = blockIdx.z;

  { // q tile + lk rows + zero histogram
    int r = tid >> 4, c4 = (tid & 15) * 4;
    *(float4*)&qbuf[r][c4] =
        *(const float4*)(q + ((size_t)b * NFULL + i0 + r) * ld + h * HD + c4);
    for (int f = tid; f < TI * 81; f += 256) {
      int rr = f / 81, c = f - rr * 81;
      lkb[rr][c] = lk[(((size_t)b * NH + h) * NFULL + i0 + rr) * 81 + c];
      wb[rr][c] = 0.f;
    }
  }
  __syncthreads();

  const int iq = tid >> 5;   // 0..7  -> rows 2iq, 2iq+1
  const int jg = tid & 31;   // 0..31
  const int slotm = jg & 15;

  // ---- phase 1: scores ----
  for (int t0 = 0; t0 < NFULL; t0 += TJ) {
    __syncthreads();
#pragma unroll
    for (int it = 0; it < 8; ++it) {
      int e = tid + it * 256;
      int r = e >> 4, c4 = e & 15;
      int slot = c4 ^ (r & 15);
      *(float4*)&kvf[r * 64 + slot * 4] =
          *(const float4*)(k + ((size_t)b * NFULL + t0 + r) * ld + h * HD + c4 * 4);
    }
    __syncthreads();
    float s[2][4] = {};
#pragma unroll
    for (int d4 = 0; d4 < 16; ++d4) {
      float q0[4], q1[4];
      *(float4*)q0 = *(const float4*)&qbuf[2 * iq][d4 * 4];
      *(float4*)q1 = *(const float4*)&qbuf[2 * iq + 1][d4 * 4];
#pragma unroll
      for (int t = 0; t < 4; ++t) {
        int jl = jg + 32 * t;
        float kv4[4];
        *(float4*)kv4 = *(const float4*)&kvf[jl * 64 + (d4 ^ slotm) * 4];
#pragma unroll
        for (int u = 0; u < 4; ++u) {
          s[0][t] = fmaf(q0[u], kv4[u], s[0][t]);
          s[1][t] = fmaf(q1[u], kv4[u], s[1][t]);
        }
      }
    }
#pragma unroll
    for (int r = 0; r < 2; ++r)
#pragma unroll
      for (int t = 0; t < 4; ++t) {
        int i = 2 * iq + r;
        int j = t0 + jg + 32 * t;
        int bb = bucket[(size_t)(i0 + i) * NFULL + j];
        float sv = s[r][t] * 0.125f + lkb[i][bb] +
                   lq[((size_t)(b * NH + h) * NFULL + j) * 81 + (80 - bb)];
        sc[i][j] = sv;
      }
  }
  __syncthreads();

  // ---- phase 2: softmax (unnormalized) + bucket histogram ----
  {
    int wid = tid >> 6, lane = tid & 63;
    for (int r = 0; r < 4; ++r) {
      int i = wid * 4 + r;
      float m = -3.4e38f;
#pragma unroll
      for (int t = 0; t < 16; ++t) m = fmaxf(m, sc[i][lane + 64 * t]);
#pragma unroll
      for (int off = 32; off; off >>= 1) m = fmaxf(m, __shfl_xor(m, off));
      float sum = 0.f;
#pragma unroll
      for (int t = 0; t < 16; ++t) {
        int j = lane + 64 * t;
        float p = expf(sc[i][j] - m);
        sc[i][j] = p;
        sum += p;
        int bb = bucket[(size_t)(i0 + i) * NFULL + j];
        atomicAdd(&wb[i][bb], p);
      }
#pragma unroll
      for (int off = 32; off; off >>= 1) sum += __shfl_xor(sum, off);
      if (!lane) rowsum[i] = sum;
    }
  }

  // ---- phase 3: PV ----
  const int dg = tid & 15;
  const int js = (tid >> 4) & 1;
  float acc0[4] = {}, acc1[4] = {};
  for (int t0 = 0; t0 < NFULL; t0 += TJ) {
    __syncthreads();
#pragma unroll
    for (int it = 0; it < 8; ++it) {
      int e = tid + it * 256;
      int r = e >> 4, c4 = e & 15;
      int slot = c4 ^ (r & 15);
      *(float4*)&kvf[r * 64 + slot * 4] =
          *(const float4*)(v + ((size_t)b * NFULL + t0 + r) * ld + h * HD + c4 * 4);
    }
    __syncthreads();
#pragma unroll
    for (int cc = 0; cc < 16; ++cc) {
      int jc = (cc * 2 + js) * 4;
      float p0[4], p1[4];
      *(float4*)p0 = *(const float4*)&sc[2 * iq][t0 + jc];
      *(float4*)p1 = *(const float4*)&sc[2 * iq + 1][t0 + jc];
#pragma unroll
      for (int u = 0; u < 4; ++u) {
        int jl = jc + u;
        float vv[4];
        *(float4*)vv = *(const float4*)&kvf[jl * 64 + ((dg ^ (jl & 15)) * 4)];
#pragma unroll
        for (int c = 0; c < 4; ++c) {
          acc0[c] = fmaf(p0[u], vv[c], acc0[c]);
          acc1[c] = fmaf(p1[u], vv[c], acc1[c]);
        }
      }
    }
  }
  // combine the two j-split halves (lanes l and l^16)
#pragma unroll
  for (int c = 0; c < 4; ++c) {
    acc0[c] += __shfl_xor(acc0[c], 16);
    acc1[c] += __shfl_xor(acc1[c], 16);
  }

  // ---- phase 4: bucket-table term + normalize + write ----
  if (js == 0) {
#pragma unroll
    for (int r2 = 0; r2 < 2; ++r2) {
      int i = 2 * iq + r2;
      float a[4];
#pragma unroll
      for (int c = 0; c < 4; ++c) a[c] = r2 ? acc1[c] : acc0[c];
      for (int c = 0; c < 81; ++c) {
        float w = wb[i][c];
        float tvv[4];
        *(float4*)tvv = *(const float4*)(tv + c * HD + dg * 4);
#pragma unroll
        for (int u = 0; u < 4; ++u) a[u] = fmaf(w, tvv[u], a[u]);
      }
      float rs = 1.0f / rowsum[i];
#pragma unroll
      for (int u = 0; u < 4; ++u) a[u] *= rs;
      *(float4*)(o + ((size_t)b * NFULL + i0 + i) * CDIM + h * HD + dg * 4) = *(float4*)a;
    }
  }
}

// ---------------- launch ----------------
extern "C" void kernel_launch(void* const* d_in, const int* in_sizes, int n_in,
                              void* d_out, int out_size, void* d_ws, size_t ws_size,
                              hipStream_t stream) {
  (void)in_sizes; (void)n_in; (void)out_size; (void)ws_size;
  const float* x0 = (const float*)d_in[0];
  const float* x1 = (const float*)d_in[1];
  const float* ln00_g = (const float*)d_in[2];
  const float* ln00_b = (const float*)d_in[3];
  const float* ln01_g = (const float*)d_in[4];
  const float* ln01_b = (const float*)d_in[5];
  const float* ln10_g = (const float*)d_in[6];
  const float* ln10_b = (const float*)d_in[7];
  const float* ln11_g = (const float*)d_in[8];
  const float* ln11_b = (const float*)d_in[9];
  const float* w_qkv0 = (const float*)d_in[10];
  const float* b_qkv0 = (const float*)d_in[11];
  const float* w_qkv1 = (const float*)d_in[12];
  const float* b_qkv1 = (const float*)d_in[13];
  const float* w_proj = (const float*)d_in[14];
  const float* b_proj = (const float*)d_in[15];
  const float* table_q = (const float*)d_in[16];
  const float* table_k = (const float*)d_in[17];
  const float* table_v = (const float*)d_in[18];
  const float* w_fc1_0 = (const float*)d_in[19];
  const float* b_fc1_0 = (const float*)d_in[20];
  const float* w_fc2_0 = (const float*)d_in[21];
  const float* b_fc2_0 = (const float*)d_in[22];
  const float* w_fc1_1 = (const float*)d_in[23];
  const float* b_fc1_1 = (const float*)d_in[24];
  const float* w_fc2_1 = (const float*)d_in[25];
  const float* b_fc2_1 = (const float*)d_in[26];

  char* base = (char*)d_ws;
  int*   bucket = (int*)base;                                   // 4 MB
  float* xn     = (float*)(base + 4194304);                     // 8 MB
  float* qkv0   = (float*)(base + 4194304 + 8388608);           // 24 MB
  float* qkv1   = qkv0 + (size_t)4 * 1024 * 1536;               // 24 MB
  float* lkbuf  = qkv1 + (size_t)4 * 1024 * 1536;               // 10.6 MB
  float* lqbuf  = lkbuf + (size_t)4 * 8 * 1024 * 81;            // 10.6 MB
  float* obuf   = lqbuf + (size_t)4 * 8 * 1024 * 81;            // 8 MB
  float* hbuf   = qkv0;  // alias: MLP hidden (32MB) reuses dead qkv region (48MB)
  float* dout0  = (float*)d_out;
  float* dout1  = dout0 + (size_t)4 * 1024 * 512;

  const int M = 4096;

  bucket_kernel<<<4096, 256, 0, stream>>>(bucket);

  ln_kernel<<<M, 256, 0, stream>>>(x0, ln00_g, ln00_b, xn);
  gemm_f32<2, 2, 0, 0><<<dim3(12, 32), 256, 0, stream>>>(xn, w_qkv0, b_qkv0, nullptr, qkv0, M, 1536, 512);
  ln_kernel<<<M, 256, 0, stream>>>(x1, ln01_g, ln01_b, xn);
  gemm_f32<2, 2, 0, 0><<<dim3(12, 32), 256, 0, stream>>>(xn, w_qkv1, b_qkv1, nullptr, qkv1, M, 1536, 512);

  // attention 0: q0 with k1/v1
  tableprod_kernel<<<M, 256, 0, stream>>>(qkv0, 1536, table_k, lkbuf, 1.0f);
  tableprod_kernel<<<M, 256, 0, stream>>>(qkv1 + 512, 1536, table_q, lqbuf, 0.125f);
  attn_kernel<<<dim3(64, 8, 4), 256, 0, stream>>>(qkv0, qkv1 + 512, qkv1 + 1024, 1536,
                                                  lkbuf, lqbuf, bucket, table_v, obuf);
  gemm_f32<2, 1, 0, 1><<<dim3(8, 32), 256, 0, stream>>>(obuf, w_proj, b_proj, x0, dout0, M, 512, 512);

  // attention 1: q1 with k0/v0
  tableprod_kernel<<<M, 256, 0, stream>>>(qkv1, 1536, table_k, lkbuf, 1.0f);
  tableprod_kernel<<<M, 256, 0, stream>>>(qkv0 + 512, 1536, table_q, lqbuf, 0.125f);
  attn_kernel<<<dim3(64, 8, 4), 256, 0, stream>>>(qkv1, qkv0 + 512, qkv0 + 1024, 1536,
                                                  lkbuf, lqbuf, bucket, table_v, obuf);
  gemm_f32<2, 1, 0, 1><<<dim3(8, 32), 256, 0, stream>>>(obuf, w_proj, b_proj, x1, dout1, M, 512, 512);

  // MLP 0
  ln_kernel<<<M, 256, 0, stream>>>(dout0, ln10_g, ln10_b, xn);
  gemm_f32<2, 2, 1, 0><<<dim3(16, 32), 256, 0, stream>>>(xn, w_fc1_0, b_fc1_0, nullptr, hbuf, M, 2048, 512);
  gemm_f32<2, 1, 0, 1><<<dim3(8, 32), 256, 0, stream>>>(hbuf, w_fc2_0, b_fc2_0, dout0, dout0, M, 512, 2048);

  // MLP 1
  ln_kernel<<<M, 256, 0, stream>>>(dout1, ln11_g, ln11_b, xn);
  gemm_f32<2, 2, 1, 0><<<dim3(16, 32), 256, 0, stream>>>(xn, w_fc1_1, b_fc1_1, nullptr, hbuf, M, 2048, 512);
  gemm_f32<2, 1, 0, 1><<<dim3(8, 32), 256, 0, stream>>>(hbuf, w_fc2_1, b_fc2_1, dout1, dout1, M, 512, 2048);
}

// Round 2
// 2157.527 us; speedup vs baseline: 1.3920x; 1.3920x over previous
//
#include <hip/hip_runtime.h>
#include <math.h>

#define NFULL 1024
#define CDIM  512
#define HD    64
#define NH    8
#define TI    16

// ---------------- bucket ids ----------------
__device__ __forceinline__ int pwidx(int d) {
  int ad = d < 0 ? -d : d;
  if (ad <= 1) return d;                       // |d| <= 1.9, d integer
  float v = 1.9f + logf((float)ad * (1.0f / 1.9f)) * (1.9f / 2.0794415416798357f); // ln(8)
  v = fminf(v, 3.8f);
  int m = (int)rintf(v);                       // round-half-even, matches jnp.round
  if (m > 4) m = 4;
  return d > 0 ? m : -m;
}

__global__ __launch_bounds__(256) void bucket_kernel(int* __restrict__ bucket) {
  int idx = blockIdx.x * 256 + threadIdx.x;    // over N*N
  int i = idx >> 10, j = idx & 1023;
  int iy = i >> 5, ix = i & 31, jy = j >> 5, jx = j & 31;
  bucket[idx] = (pwidx(iy - jy) + 4) * 9 + (pwidx(ix - jx) + 4);
}

// ---------------- layernorm (one block per row of 512) ----------------
__global__ __launch_bounds__(256) void ln_kernel(const float* __restrict__ x,
                                                 const float* __restrict__ g,
                                                 const float* __restrict__ be,
                                                 float* __restrict__ y) {
  __shared__ float red[8];
  int row = blockIdx.x, tid = threadIdx.x;
  const float* xr = x + (size_t)row * CDIM;
  float v0 = xr[tid], v1 = xr[tid + 256];
  float s = v0 + v1;
#pragma unroll
  for (int off = 32; off; off >>= 1) s += __shfl_xor(s, off);
  int wid = tid >> 6, lane = tid & 63;
  if (!lane) red[wid] = s;
  __syncthreads();
  float mu = (red[0] + red[1] + red[2] + red[3]) * (1.0f / 512.0f);
  float d0 = v0 - mu, d1 = v1 - mu;
  float q = d0 * d0 + d1 * d1;
#pragma unroll
  for (int off = 32; off; off >>= 1) q += __shfl_xor(q, off);
  if (!lane) red[4 + wid] = q;
  __syncthreads();
  float var = (red[4] + red[5] + red[6] + red[7]) * (1.0f / 512.0f);
  float rstd = rsqrtf(var + 1e-5f);
  float* yr = y + (size_t)row * CDIM;
  yr[tid]       = d0 * rstd * g[tid]       + be[tid];
  yr[tid + 256] = d1 * rstd * g[tid + 256] + be[tid + 256];
}

// ---------------- generic fp32 GEMM: C = act(A@B + bias) (+res) ----------------
__device__ __forceinline__ float gelu_f(float x) {
  return 0.5f * x * (1.0f + erff(x * 0.7071067811865475f));
}

template <int RG, int CG, int ACT, int RES>
__global__ __launch_bounds__(256) void gemm_f32(const float* __restrict__ A,
                                                const float* __restrict__ Bm,
                                                const float* __restrict__ bias,
                                                const float* __restrict__ res,
                                                float* __restrict__ C,
                                                int M, int N, int K) {
  constexpr int BM = 64 * RG, BN = 64 * CG, BK = 32;
  __shared__ __attribute__((aligned(16))) float As[BK][BM + 4];  // transposed: As[k][m]
  __shared__ __attribute__((aligned(16))) float Bs[BK][BN + 4];
  const int tid = threadIdx.x;
  const int bm = blockIdx.y * BM, bn = blockIdx.x * BN;
  const int ty = tid >> 4, tx = tid & 15;
  float acc[4 * RG][4 * CG] = {};

  for (int k0 = 0; k0 < K; k0 += BK) {
    __syncthreads();
#pragma unroll
    for (int it = 0; it < RG * 2; ++it) {
      int e = tid + it * 256;
      int ar = e >> 3, ac = (e & 7) * 4;
      float4 av = *(const float4*)(A + (size_t)(bm + ar) * K + k0 + ac);
      As[ac + 0][ar] = av.x; As[ac + 1][ar] = av.y;
      As[ac + 2][ar] = av.z; As[ac + 3][ar] = av.w;
    }
#pragma unroll
    for (int it = 0; it < CG * 2; ++it) {
      int e = tid + it * 256;
      int br, bc;
      if (CG == 2) { br = e >> 5; bc = (e & 31) * 4; }
      else         { br = e >> 4; bc = (e & 15) * 4; }
      *(float4*)&Bs[br][bc] = *(const float4*)(Bm + (size_t)(k0 + br) * N + bn + bc);
    }
    __syncthreads();
#pragma unroll
    for (int kk = 0; kk < BK; ++kk) {
      float a[4 * RG], b[4 * CG];
#pragma unroll
      for (int rg = 0; rg < RG; ++rg)
        *(float4*)&a[rg * 4] = *(const float4*)&As[kk][(ty + 16 * rg) * 4];
#pragma unroll
      for (int cg = 0; cg < CG; ++cg)
        *(float4*)&b[cg * 4] = *(const float4*)&Bs[kk][(tx + 16 * cg) * 4];
#pragma unroll
      for (int i = 0; i < 4 * RG; ++i)
#pragma unroll
        for (int j = 0; j < 4 * CG; ++j)
          acc[i][j] = fmaf(a[i], b[j], acc[i][j]);
    }
  }
  // epilogue
  float bv[4 * CG];
#pragma unroll
  for (int cg = 0; cg < CG; ++cg)
    *(float4*)&bv[cg * 4] = *(const float4*)(bias + bn + (tx + 16 * cg) * 4);
#pragma unroll
  for (int rg = 0; rg < RG; ++rg) {
#pragma unroll
    for (int r = 0; r < 4; ++r) {
      int row = bm + (ty + 16 * rg) * 4 + r;
#pragma unroll
      for (int cg = 0; cg < CG; ++cg) {
        int col = bn + (tx + 16 * cg) * 4;
        float o[4];
#pragma unroll
        for (int c = 0; c < 4; ++c) {
          float v = acc[rg * 4 + r][cg * 4 + c] + bv[cg * 4 + c];
          if (ACT == 1) v = gelu_f(v);
          o[c] = v;
        }
        if (RES) {
          float rr[4];
          *(float4*)rr = *(const float4*)(res + (size_t)row * N + col);
#pragma unroll
          for (int c = 0; c < 4; ++c) o[c] += rr[c];
        }
        *(float4*)(C + (size_t)row * N + col) = *(float4*)o;
      }
    }
  }
}

// ---------------- table products: out[b,h,i,c] = scl * dot(X[b,i,h*64:+64], T[c,:]) ----------------
__global__ __launch_bounds__(256) void tableprod_kernel(const float* __restrict__ X, int ldx,
                                                        const float* __restrict__ T,
                                                        float* __restrict__ out, float scl) {
  __shared__ __attribute__((aligned(16))) float Ts[81 * 65];
  __shared__ __attribute__((aligned(16))) float xr[512];
  int r = blockIdx.x;  // b*N + i
  int tid = threadIdx.x;
  for (int f = tid; f < 81 * 64; f += 256) Ts[(f >> 6) * 65 + (f & 63)] = T[f];
  xr[tid]       = X[(size_t)r * ldx + tid];
  xr[tid + 256] = X[(size_t)r * ldx + tid + 256];
  __syncthreads();
  int b = r >> 10, i = r & 1023;
  for (int f = tid; f < NH * 81; f += 256) {
    int hh = f / 81, c = f - hh * 81;
    const float* xp = &xr[hh * 64];
    const float* tp = &Ts[c * 65];
    float dot = 0.f;
#pragma unroll
    for (int d = 0; d < 64; ++d) dot = fmaf(xp[d], tp[d], dot);
    out[((size_t)(b * NH + hh) * NFULL + i) * 81 + c] = dot * scl;
  }
}

// ---------------- fused attention (scores in registers) ----------------
// block = (b, h, 16 q-rows), 256 threads = 4 waves. Wave w owns rows 4w..4w+3.
// Lane l holds score s[r][tt] for j = l + 64*tt  (tt = 0..15).
__global__ __launch_bounds__(256, 3) void attn_kernel(const float* __restrict__ q,
                                                      const float* __restrict__ k,
                                                      const float* __restrict__ v,
                                                      int ld,
                                                      const float* __restrict__ lk,
                                                      const float* __restrict__ lq,
                                                      const int* __restrict__ bucket,
                                                      const float* __restrict__ tv,
                                                      float* __restrict__ o) {
  __shared__ __attribute__((aligned(16))) float kbuf[8192];      // 32 KB union buffer
  __shared__ __attribute__((aligned(16))) float qbuf[TI][HD];    // 4 KB
  __shared__ float lkb[TI][81];                                  // 5.2 KB
  __shared__ float wb[TI][81];                                   // 5.2 KB

  const int tid = threadIdx.x;
  const int i0 = blockIdx.x * TI;
  const int h = blockIdx.y;
  const int b = blockIdx.z;
  const int w = tid >> 6;       // wave id (0..3)
  const int l = tid & 63;       // lane
  const size_t bh = (size_t)(b * NH + h);

  // ---- prologue: q tile + lk rows + zero histogram ----
  {
    int r = tid >> 4, c4 = (tid & 15) * 4;
    *(float4*)&qbuf[r][c4] =
        *(const float4*)(q + ((size_t)b * NFULL + i0 + r) * ld + h * HD + c4);
    for (int f = tid; f < TI * 81; f += 256) {
      int rr = f / 81, c = f - rr * 81;
      lkb[rr][c] = lk[(bh * NFULL + i0 + rr) * 81 + c];
      wb[rr][c] = 0.f;
    }
  }

  float s[4][16];
#pragma unroll
  for (int r = 0; r < 4; ++r)
#pragma unroll
    for (int t = 0; t < 16; ++t) s[r][t] = 0.f;

  const int slotm = l & 15;

  // ---- phase 1: QK^T, k staged in 128-row LDS tiles ----
  for (int T = 0; T < 8; ++T) {
    __syncthreads();
#pragma unroll
    for (int it = 0; it < 8; ++it) {
      int e = tid + it * 256;
      int r = e >> 4, c4 = e & 15;
      int slot = c4 ^ (r & 15);
      *(float4*)&kbuf[r * 64 + slot * 4] =
          *(const float4*)(k + ((size_t)b * NFULL + T * 128 + r) * ld + h * HD + c4 * 4);
    }
    __syncthreads();
#pragma unroll
    for (int d4 = 0; d4 < 16; ++d4) {
      float k1[4], k2[4];
      *(float4*)k1 = *(const float4*)&kbuf[l * 64 + ((d4 ^ slotm) * 4)];
      *(float4*)k2 = *(const float4*)&kbuf[(l + 64) * 64 + ((d4 ^ slotm) * 4)];
#pragma unroll
      for (int r = 0; r < 4; ++r) {
        float qv[4];
        *(float4*)qv = *(const float4*)&qbuf[4 * w + r][d4 * 4];
#pragma unroll
        for (int u = 0; u < 4; ++u) {
          s[r][2 * T]     = fmaf(qv[u], k1[u], s[r][2 * T]);
          s[r][2 * T + 1] = fmaf(qv[u], k2[u], s[r][2 * T + 1]);
        }
      }
    }
  }

  // ---- phase 2: biases (lq staged per 64-row tile in kbuf) ----
  for (int tt = 0; tt < 16; ++tt) {
    __syncthreads();
    {
      const float* src = lq + (bh * NFULL + tt * 64) * 81;
      for (int f = tid; f < 64 * 81; f += 256) kbuf[f] = src[f];
    }
    __syncthreads();
#pragma unroll
    for (int r = 0; r < 4; ++r) {
      int i = 4 * w + r;
      int bb = bucket[(size_t)(i0 + i) * NFULL + tt * 64 + l];
      s[r][tt] = s[r][tt] * 0.125f + lkb[i][bb] + kbuf[l * 81 + (80 - bb)];
    }
  }

  // ---- phase 3: softmax (unnormalized, regs) + bucket histogram ----
  float sum4[4];
#pragma unroll
  for (int r = 0; r < 4; ++r) {
    int i = 4 * w + r;
    float m = -3.4e38f;
#pragma unroll
    for (int t = 0; t < 16; ++t) m = fmaxf(m, s[r][t]);
#pragma unroll
    for (int off = 32; off; off >>= 1) m = fmaxf(m, __shfl_xor(m, off));
    float psum = 0.f;
#pragma unroll
    for (int t = 0; t < 16; ++t) {
      int bb = bucket[(size_t)(i0 + i) * NFULL + t * 64 + l];
      float p = expf(s[r][t] - m);
      s[r][t] = p;
      psum += p;
      atomicAdd(&wb[i][bb], p);
    }
#pragma unroll
    for (int off = 32; off; off >>= 1) psum += __shfl_xor(psum, off);
    sum4[r] = psum;
  }

  // ---- phase 4: PV over 64-row v tiles; p through LDS ----
  // thread -> (rq = wave, dg = (tid>>3)&7 : 8 floats of d, js = tid&7 : 8 j's)
  const int dg = (tid >> 3) & 7;
  const int js = tid & 7;
  float* vbuf = kbuf;            // [64][64] swizzled, 16 KB
  float* pbuf = kbuf + 4096;     // [16][64], 4 KB
  float acc[4][8];
#pragma unroll
  for (int r = 0; r < 4; ++r)
#pragma unroll
    for (int c = 0; c < 8; ++c) acc[r][c] = 0.f;

  for (int T = 0; T < 16; ++T) {
    __syncthreads();
#pragma unroll
    for (int it = 0; it < 4; ++it) {
      int e = tid + it * 256;
      int r = e >> 4, c4 = e & 15;
      int slot = (c4 >> 1) ^ (r & 7);
      *(float4*)&vbuf[r * 64 + slot * 8 + (c4 & 1) * 4] =
          *(const float4*)(v + ((size_t)b * NFULL + T * 64 + r) * ld + h * HD + c4 * 4);
    }
#pragma unroll
    for (int r = 0; r < 4; ++r) pbuf[(4 * w + r) * 64 + l] = s[r][T];
    __syncthreads();
#pragma unroll
    for (int jj = 0; jj < 8; ++jj) {
      int j = js * 8 + jj;
      int slot = dg ^ jj;                   // j & 7 == jj
      float v0[4], v1[4];
      *(float4*)v0 = *(const float4*)&vbuf[j * 64 + slot * 8];
      *(float4*)v1 = *(const float4*)&vbuf[j * 64 + slot * 8 + 4];
#pragma unroll
      for (int r = 0; r < 4; ++r) {
        float p = pbuf[(4 * w + r) * 64 + j];
#pragma unroll
        for (int c = 0; c < 4; ++c) {
          acc[r][c]     = fmaf(p, v0[c], acc[r][c]);
          acc[r][4 + c] = fmaf(p, v1[c], acc[r][4 + c]);
        }
      }
    }
  }

  // ---- phase 5: tv-bucket term (parallel over js), reduce, normalize, store ----
#pragma unroll
  for (int cc = 0; cc <= 10; ++cc) {
    int c = cc * 8 + js;
    if (c < 81) {
      float t0[4], t1[4];
      *(float4*)t0 = *(const float4*)(tv + c * HD + dg * 8);
      *(float4*)t1 = *(const float4*)(tv + c * HD + dg * 8 + 4);
#pragma unroll
      for (int r = 0; r < 4; ++r) {
        float wv = wb[4 * w + r][c];
#pragma unroll
        for (int u = 0; u < 4; ++u) {
          acc[r][u]     = fmaf(wv, t0[u], acc[r][u]);
          acc[r][4 + u] = fmaf(wv, t1[u], acc[r][4 + u]);
        }
      }
    }
  }
#pragma unroll
  for (int off = 1; off <= 4; off <<= 1)
#pragma unroll
    for (int r = 0; r < 4; ++r)
#pragma unroll
      for (int c = 0; c < 8; ++c) acc[r][c] += __shfl_xor(acc[r][c], off);

  if (js == 0) {
#pragma unroll
    for (int r = 0; r < 4; ++r) {
      float rn = 1.0f / sum4[r];
      float o0[4], o1[4];
#pragma unroll
      for (int u = 0; u < 4; ++u) { o0[u] = acc[r][u] * rn; o1[u] = acc[r][4 + u] * rn; }
      float* op = o + ((size_t)b * NFULL + i0 + 4 * w + r) * CDIM + h * HD + dg * 8;
      *(float4*)op       = *(float4*)o0;
      *(float4*)(op + 4) = *(float4*)o1;
    }
  }
}

// ---------------- launch ----------------
extern "C" void kernel_launch(void* const* d_in, const int* in_sizes, int n_in,
                              void* d_out, int out_size, void* d_ws, size_t ws_size,
                              hipStream_t stream) {
  (void)in_sizes; (void)n_in; (void)out_size; (void)ws_size;
  const float* x0 = (const float*)d_in[0];
  const float* x1 = (const float*)d_in[1];
  const float* ln00_g = (const float*)d_in[2];
  const float* ln00_b = (const float*)d_in[3];
  const float* ln01_g = (const float*)d_in[4];
  const float* ln01_b = (const float*)d_in[5];
  const float* ln10_g = (const float*)d_in[6];
  const float* ln10_b = (const float*)d_in[7];
  const float* ln11_g = (const float*)d_in[8];
  const float* ln11_b = (const float*)d_in[9];
  const float* w_qkv0 = (const float*)d_in[10];
  const float* b_qkv0 = (const float*)d_in[11];
  const float* w_qkv1 = (const float*)d_in[12];
  const float* b_qkv1 = (const float*)d_in[13];
  const float* w_proj = (const float*)d_in[14];
  const float* b_proj = (const float*)d_in[15];
  const float* table_q = (const float*)d_in[16];
  const float* table_k = (const float*)d_in[17];
  const float* table_v = (const float*)d_in[18];
  const float* w_fc1_0 = (const float*)d_in[19];
  const float* b_fc1_0 = (const float*)d_in[20];
  const float* w_fc2_0 = (const float*)d_in[21];
  const float* b_fc2_0 = (const float*)d_in[22];
  const float* w_fc1_1 = (const float*)d_in[23];
  const float* b_fc1_1 = (const float*)d_in[24];
  const float* w_fc2_1 = (const float*)d_in[25];
  const float* b_fc2_1 = (const float*)d_in[26];

  char* base = (char*)d_ws;
  int*   bucket = (int*)base;                                   // 4 MB
  float* xn     = (float*)(base + 4194304);                     // 8 MB
  float* qkv0   = (float*)(base + 4194304 + 8388608);           // 24 MB
  float* qkv1   = qkv0 + (size_t)4 * 1024 * 1536;               // 24 MB
  float* lkbuf  = qkv1 + (size_t)4 * 1024 * 1536;               // 10.6 MB
  float* lqbuf  = lkbuf + (size_t)4 * 8 * 1024 * 81;            // 10.6 MB
  float* obuf   = lqbuf + (size_t)4 * 8 * 1024 * 81;            // 8 MB
  float* hbuf   = qkv0;  // alias: MLP hidden (32MB) reuses dead qkv region (48MB)
  float* dout0  = (float*)d_out;
  float* dout1  = dout0 + (size_t)4 * 1024 * 512;

  const int M = 4096;

  bucket_kernel<<<4096, 256, 0, stream>>>(bucket);

  ln_kernel<<<M, 256, 0, stream>>>(x0, ln00_g, ln00_b, xn);
  gemm_f32<2, 2, 0, 0><<<dim3(12, 32), 256, 0, stream>>>(xn, w_qkv0, b_qkv0, nullptr, qkv0, M, 1536, 512);
  ln_kernel<<<M, 256, 0, stream>>>(x1, ln01_g, ln01_b, xn);
  gemm_f32<2, 2, 0, 0><<<dim3(12, 32), 256, 0, stream>>>(xn, w_qkv1, b_qkv1, nullptr, qkv1, M, 1536, 512);

  // attention 0: q0 with k1/v1
  tableprod_kernel<<<M, 256, 0, stream>>>(qkv0, 1536, table_k, lkbuf, 1.0f);
  tableprod_kernel<<<M, 256, 0, stream>>>(qkv1 + 512, 1536, table_q, lqbuf, 0.125f);
  attn_kernel<<<dim3(64, 8, 4), 256, 0, stream>>>(qkv0, qkv1 + 512, qkv1 + 1024, 1536,
                                                  lkbuf, lqbuf, bucket, table_v, obuf);
  gemm_f32<2, 1, 0, 1><<<dim3(8, 32), 256, 0, stream>>>(obuf, w_proj, b_proj, x0, dout0, M, 512, 512);

  // attention 1: q1 with k0/v0
  tableprod_kernel<<<M, 256, 0, stream>>>(qkv1, 1536, table_k, lkbuf, 1.0f);
  tableprod_kernel<<<M, 256, 0, stream>>>(qkv0 + 512, 1536, table_q, lqbuf, 0.125f);
  attn_kernel<<<dim3(64, 8, 4), 256, 0, stream>>>(qkv1, qkv0 + 512, qkv0 + 1024, 1536,
                                                  lkbuf, lqbuf, bucket, table_v, obuf);
  gemm_f32<2, 1, 0, 1><<<dim3(8, 32), 256, 0, stream>>>(obuf, w_proj, b_proj, x1, dout1, M, 512, 512);

  // MLP 0
  ln_kernel<<<M, 256, 0, stream>>>(dout0, ln10_g, ln10_b, xn);
  gemm_f32<2, 2, 1, 0><<<dim3(16, 32), 256, 0, stream>>>(xn, w_fc1_0, b_fc1_0, nullptr, hbuf, M, 2048, 512);
  gemm_f32<2, 1, 0, 1><<<dim3(8, 32), 256, 0, stream>>>(hbuf, w_fc2_0, b_fc2_0, dout0, dout0, M, 512, 2048);

  // MLP 1
  ln_kernel<<<M, 256, 0, stream>>>(dout1, ln11_g, ln11_b, xn);
  gemm_f32<2, 2, 1, 0><<<dim3(16, 32), 256, 0, stream>>>(xn, w_fc1_1, b_fc1_1, nullptr, hbuf, M, 2048, 512);
  gemm_f32<2, 1, 0, 1><<<dim3(8, 32), 256, 0, stream>>>(hbuf, w_fc2_1, b_fc2_1, dout1, dout1, M, 512, 2048);
}